// Round 5
// baseline (856.138 us; speedup 1.0000x reference)
//
#include <hip/hip_runtime.h>
#include <hip/hip_bf16.h>
#include <math.h>

#define SEQ 2048
#define DIM 2048
#define NHEAD 16
#define HD 128
#define HIDDEN 5632
#define QKVN 6144
constexpr float EPS = 1e-6f;

typedef __hip_bfloat16 bf16;
using short8  = __attribute__((ext_vector_type(8))) short;
using short4v = __attribute__((ext_vector_type(4))) short;
using floatx4 = __attribute__((ext_vector_type(4))) float;

__device__ inline void gl_lds16(const void* g, void* l) {
    __builtin_amdgcn_global_load_lds((const __attribute__((address_space(1))) void*)g,
                                     (__attribute__((address_space(3))) void*)l, 16, 0, 0);
}

// ---------------------------------------------------------------- rmsnorm (f32 in, bf16 out), float4 vectorized
__global__ __launch_bounds__(256) void rmsnorm_kernel(const float* __restrict__ x,
                                                      const float* __restrict__ g,
                                                      bf16* __restrict__ out) {
    const int row = blockIdx.x;
    const int t = threadIdx.x;
    const float* xr = x + (size_t)row * DIM + t * 8;
    float4 a = *(const float4*)xr;
    float4 b = *(const float4*)(xr + 4);
    float ss = a.x*a.x + a.y*a.y + a.z*a.z + a.w*a.w
             + b.x*b.x + b.y*b.y + b.z*b.z + b.w*b.w;
    __shared__ float red[256];
    red[t] = ss;
    __syncthreads();
    for (int s = 128; s > 0; s >>= 1) {
        if (t < s) red[t] += red[t + s];
        __syncthreads();
    }
    float sc = rsqrtf(red[0] / (float)DIM + EPS);
    float4 g1 = *(const float4*)(g + t * 8);
    float4 g2 = *(const float4*)(g + t * 8 + 4);
    bf16 tmp[8];
    tmp[0] = __float2bfloat16(a.x * sc * g1.x);
    tmp[1] = __float2bfloat16(a.y * sc * g1.y);
    tmp[2] = __float2bfloat16(a.z * sc * g1.z);
    tmp[3] = __float2bfloat16(a.w * sc * g1.w);
    tmp[4] = __float2bfloat16(b.x * sc * g2.x);
    tmp[5] = __float2bfloat16(b.y * sc * g2.y);
    tmp[6] = __float2bfloat16(b.z * sc * g2.z);
    tmp[7] = __float2bfloat16(b.w * sc * g2.w);
    *(uint4*)(out + (size_t)row * DIM + t * 8) = *(uint4*)tmp;
}

// ---------------------------------------------------------------- weight cast+transpose, float4, z-batched
// in [K][N] f32 -> out [N][K] bf16 ; blockIdx.z selects source (in0/in1/in2), dst offset z*K*N
__global__ __launch_bounds__(256) void cvt_t_kernel(const float* __restrict__ in0,
                                                    const float* __restrict__ in1,
                                                    const float* __restrict__ in2,
                                                    bf16* __restrict__ out,
                                                    int K, int N) {
    const float* in = (blockIdx.z == 0) ? in0 : (blockIdx.z == 1) ? in1 : in2;
    bf16* o = out + (size_t)blockIdx.z * K * N;
    __shared__ float tile[64][65];
    const int nb = blockIdx.x * 64, kb = blockIdx.y * 64;
    const int tc = threadIdx.x & 15, tr = threadIdx.x >> 4;
#pragma unroll
    for (int u = 0; u < 4; ++u) {
        int r = tr + u * 16;
        float4 v = *(const float4*)(in + (size_t)(kb + r) * N + nb + tc * 4);
        tile[r][tc * 4 + 0] = v.x;
        tile[r][tc * 4 + 1] = v.y;
        tile[r][tc * 4 + 2] = v.z;
        tile[r][tc * 4 + 3] = v.w;
    }
    __syncthreads();
#pragma unroll
    for (int u = 0; u < 4; ++u) {
        int rr = tr + u * 16;
        bf16 tmp[4];
#pragma unroll
        for (int j = 0; j < 4; ++j)
            tmp[j] = __float2bfloat16(tile[tc * 4 + j][rr]);
        *(uint2*)(o + (size_t)(nb + rr) * K + kb + tc * 4) = *(uint2*)tmp;
    }
}

// ---------------------------------------------------------------- bf16 MFMA GEMM (m97 structure)
// MODE 0: bf16 C = AB   MODE 1: f32 C = AB + R
template <int MODE>
__global__ __launch_bounds__(256) void gemm_bf16(const bf16* __restrict__ A,
                                                 const bf16* __restrict__ Bt,
                                                 void* __restrict__ Cv,
                                                 const float* __restrict__ R,
                                                 int K, int ldc) {
    __shared__ bf16 Asm[128 * 32];
    __shared__ bf16 Bsm[128 * 32];
    const int t = threadIdx.x;
    const int m0 = blockIdx.y * 128;
    const int n0 = blockIdx.x * 128;
    const int lane = t & 63;
    const int wave = t >> 6;
    const int wr = wave >> 1, wc = wave & 1;
    const int quad = lane >> 4;
    const int l16 = lane & 15;

    floatx4 acc[4][4] = {};

    const int ar = t >> 2;
    const int ak = (t & 3) * 8;
    const bf16* Ag = A + (size_t)(m0 + ar) * K + ak;
    const bf16* Bg = Bt + (size_t)(n0 + ar) * K + ak;
    bf16* Al = Asm + t * 8;
    bf16* Bl = Bsm + t * 8;
    const size_t half = (size_t)64 * K;

    for (int k0 = 0; k0 < K; k0 += 32) {
        __syncthreads();
        gl_lds16(Ag + k0, Al);
        gl_lds16(Ag + k0 + half, Al + 64 * 32);
        gl_lds16(Bg + k0, Bl);
        gl_lds16(Bg + k0 + half, Bl + 64 * 32);
        __syncthreads();

        short8 af[4], bfr[4];
#pragma unroll
        for (int i = 0; i < 4; ++i)
            af[i] = *(const short8*)(Asm + (wr * 64 + i * 16 + l16) * 32 + quad * 8);
#pragma unroll
        for (int j = 0; j < 4; ++j)
            bfr[j] = *(const short8*)(Bsm + (wc * 64 + j * 16 + l16) * 32 + quad * 8);
#pragma unroll
        for (int i = 0; i < 4; ++i)
#pragma unroll
            for (int j = 0; j < 4; ++j)
                acc[i][j] = __builtin_amdgcn_mfma_f32_16x16x32_bf16(af[i], bfr[j], acc[i][j], 0, 0, 0);
    }

#pragma unroll
    for (int i = 0; i < 4; ++i) {
#pragma unroll
        for (int j = 0; j < 4; ++j) {
#pragma unroll
            for (int r = 0; r < 4; ++r) {
                int m = m0 + wr * 64 + i * 16 + quad * 4 + r;
                int n = n0 + wc * 64 + j * 16 + l16;
                size_t idx = (size_t)m * ldc + n;
                float v = acc[i][j][r];
                if (MODE == 0) {
                    ((bf16*)Cv)[idx] = __float2bfloat16(v);
                } else {
                    ((float*)Cv)[idx] = v + R[idx];
                }
            }
        }
    }
}

// ---------------------------------------------------------------- fused SwiGLU GEMM
// C[M][HIDDEN] bf16 = silu(A@B1t^T) * (A@B3t^T) ; A staged once, dual accumulators.
__global__ __launch_bounds__(256) void gemm_swiglu(const bf16* __restrict__ A,
                                                   const bf16* __restrict__ B1t,
                                                   const bf16* __restrict__ B3t,
                                                   bf16* __restrict__ C,
                                                   int K, int ldc) {
    __shared__ bf16 Asm[128 * 32];
    __shared__ bf16 B1sm[128 * 32];
    __shared__ bf16 B3sm[128 * 32];
    const int t = threadIdx.x;
    const int m0 = blockIdx.y * 128;
    const int n0 = blockIdx.x * 128;
    const int lane = t & 63;
    const int wave = t >> 6;
    const int wr = wave >> 1, wc = wave & 1;
    const int quad = lane >> 4;
    const int l16 = lane & 15;

    floatx4 acc1[4][4] = {};
    floatx4 acc3[4][4] = {};

    const int ar = t >> 2;
    const int ak = (t & 3) * 8;
    const bf16* Ag  = A   + (size_t)(m0 + ar) * K + ak;
    const bf16* B1g = B1t + (size_t)(n0 + ar) * K + ak;
    const bf16* B3g = B3t + (size_t)(n0 + ar) * K + ak;
    bf16* Al  = Asm  + t * 8;
    bf16* B1l = B1sm + t * 8;
    bf16* B3l = B3sm + t * 8;
    const size_t half = (size_t)64 * K;

    for (int k0 = 0; k0 < K; k0 += 32) {
        __syncthreads();
        gl_lds16(Ag + k0, Al);
        gl_lds16(Ag + k0 + half, Al + 64 * 32);
        gl_lds16(B1g + k0, B1l);
        gl_lds16(B1g + k0 + half, B1l + 64 * 32);
        gl_lds16(B3g + k0, B3l);
        gl_lds16(B3g + k0 + half, B3l + 64 * 32);
        __syncthreads();

        short8 af[4], bfr[4];
#pragma unroll
        for (int i = 0; i < 4; ++i)
            af[i] = *(const short8*)(Asm + (wr * 64 + i * 16 + l16) * 32 + quad * 8);
#pragma unroll
        for (int j = 0; j < 4; ++j)
            bfr[j] = *(const short8*)(B1sm + (wc * 64 + j * 16 + l16) * 32 + quad * 8);
#pragma unroll
        for (int i = 0; i < 4; ++i)
#pragma unroll
            for (int j = 0; j < 4; ++j)
                acc1[i][j] = __builtin_amdgcn_mfma_f32_16x16x32_bf16(af[i], bfr[j], acc1[i][j], 0, 0, 0);
#pragma unroll
        for (int j = 0; j < 4; ++j)
            bfr[j] = *(const short8*)(B3sm + (wc * 64 + j * 16 + l16) * 32 + quad * 8);
#pragma unroll
        for (int i = 0; i < 4; ++i)
#pragma unroll
            for (int j = 0; j < 4; ++j)
                acc3[i][j] = __builtin_amdgcn_mfma_f32_16x16x32_bf16(af[i], bfr[j], acc3[i][j], 0, 0, 0);
    }

#pragma unroll
    for (int i = 0; i < 4; ++i) {
#pragma unroll
        for (int j = 0; j < 4; ++j) {
#pragma unroll
            for (int r = 0; r < 4; ++r) {
                int m = m0 + wr * 64 + i * 16 + quad * 4 + r;
                int n = n0 + wc * 64 + j * 16 + l16;
                float a1 = acc1[i][j][r];
                float a3 = acc3[i][j][r];
                float s = a1 / (1.f + __expf(-a1));
                C[(size_t)m * ldc + n] = __float2bfloat16(s * a3);
            }
        }
    }
}

// ---------------------------------------------------------------- RoPE (in-place, bf16 qkv buffer)
__global__ __launch_bounds__(256) void rope_kernel(bf16* __restrict__ qkv,
                                                   const float* __restrict__ cs,
                                                   const float* __restrict__ sn) {
    int idx = blockIdx.x * 256 + threadIdx.x;
    int d2 = idx % (HD / 2);
    int rest = idx / (HD / 2);
    int h = rest % NHEAD;
    int s = rest / NHEAD;
    float c = cs[s * (HD / 2) + d2];
    float si = sn[s * (HD / 2) + d2];
    bf16* qp = qkv + (size_t)s * QKVN + h * HD + 2 * d2;
    bf16* kp = qp + DIM;
    float qr = __bfloat162float(qp[0]), qi = __bfloat162float(qp[1]);
    qp[0] = __float2bfloat16(qr * c - qi * si);
    qp[1] = __float2bfloat16(qr * si + qi * c);
    float kr = __bfloat162float(kp[0]), ki = __bfloat162float(kp[1]);
    kp[0] = __float2bfloat16(kr * c - ki * si);
    kp[1] = __float2bfloat16(kr * si + ki * c);
}

// ---------------------------------------------------------------- MFMA flash attention, swizzled LDS + reg prefetch
// Block = 4 waves, one (head, 64-row Q tile). XOR swizzle on 16B chunks:
// chunk' = chunk ^ (row & 7) -> every frag ds_read_b128 is 2-way (free).
// K/V tile jt+1 prefetched into VGPRs during compute of tile jt.
// LDS = 40 KB. Causal balance: block b pairs with b+256 (work sums to 33).
__global__ __launch_bounds__(256, 3) void flash_attn_mfma(const bf16* __restrict__ qkv,
                                                          bf16* __restrict__ out) {
    __shared__ bf16 Ks[64 * 128];   // [key][16 chunks of 8 dims], swizzled
    __shared__ bf16 Vt[128 * 64];   // [dim][8 chunks of 8 keys], swizzled
    __shared__ bf16 Ps[64 * 64];    // [qrow][8 chunks of 8 keys], swizzled

    const int b = blockIdx.x;
    const int h = b & (NHEAD - 1);
    const int z = b >> 4;
    const int it = (z < 16) ? z : 47 - z;
    const int t = threadIdx.x;
    const int lane = t & 63;
    const int w = t >> 6;
    const int quad = lane >> 4;
    const int l16 = lane & 15;
    const int s0 = it * 64;
    const float scale = 0.08838834764831845f;   // 1/sqrt(128)

    // ---- Q strip in registers: A-frag layout m=l16, k=quad*8+j
    short8 qreg[4];
    {
        const bf16* qrow = qkv + (size_t)(s0 + 16 * w + l16) * QKVN + h * HD + quad * 8;
#pragma unroll
        for (int ks = 0; ks < 4; ++ks)
            qreg[ks] = *(const short8*)(qrow + ks * 32);
    }

    floatx4 O[8] = {};
    float m_i[4], l_i[4];
#pragma unroll
    for (int r = 0; r < 4; ++r) { m_i[r] = -INFINITY; l_i[r] = 0.f; }

    const int vkg = t >> 5;     // V stage: keys vkg*8..+7
    const int vdg = t & 31;     // V stage: dims vdg*4..+3
    const int sw7 = l16 & 7;    // frag-read swizzle key (row&7 for row=base16+l16)

    uint4 Kreg[4];
    short4v Vreg[8];

    auto load_tile = [&](int tb) {
#pragma unroll
        for (int u = 0; u < 4; ++u) {
            int id = t + 256 * u;
            int kr = id >> 4, kc = id & 15;
            Kreg[u] = *(const uint4*)(qkv + (size_t)(tb + kr) * QKVN + DIM + h * HD + kc * 8);
        }
#pragma unroll
        for (int kk = 0; kk < 8; ++kk)
            Vreg[kk] = *(const short4v*)(qkv + (size_t)(tb + vkg * 8 + kk) * QKVN + 2 * DIM + h * HD + vdg * 4);
    };

    load_tile(0);

    for (int jt = 0; jt <= it; ++jt) {
        __syncthreads();    // all waves done reading previous tile's LDS

        // ---- regs -> LDS (swizzled)
#pragma unroll
        for (int u = 0; u < 4; ++u) {
            int id = t + 256 * u;
            int kr = id >> 4, kc = id & 15;
            *(uint4*)&Ks[kr * 128 + (kc ^ (kr & 7)) * 8] = Kreg[u];
        }
#pragma unroll
        for (int dd = 0; dd < 4; ++dd) {
            int d = vdg * 4 + dd;
            short8 wv;
#pragma unroll
            for (int kk = 0; kk < 8; ++kk) wv[kk] = Vreg[kk][dd];
            *(short8*)&Vt[d * 64 + (vkg ^ (d & 7)) * 8] = wv;
        }
        __syncthreads();

        if (jt < it) load_tile((jt + 1) * 64);   // prefetch overlaps compute below

        // ---- S = Q K^T : wave strip 16 x 64
        floatx4 sacc[4] = {};
#pragma unroll
        for (int ks = 0; ks < 4; ++ks) {
            short8 kbf[4];
#pragma unroll
            for (int nt = 0; nt < 4; ++nt)
                kbf[nt] = *(const short8*)&Ks[(nt * 16 + l16) * 128 + ((ks * 4 + quad) ^ sw7) * 8];
#pragma unroll
            for (int nt = 0; nt < 4; ++nt)
                sacc[nt] = __builtin_amdgcn_mfma_f32_16x16x32_bf16(qreg[ks], kbf[nt], sacc[nt], 0, 0, 0);
        }

        // ---- scale + causal mask + online softmax
        float alpha[4];
#pragma unroll
        for (int r = 0; r < 4; ++r) {
            float mx = -INFINITY;
#pragma unroll
            for (int nt = 0; nt < 4; ++nt) {
                float s = sacc[nt][r] * scale;
                if (jt == it && (nt * 16 + l16) > (16 * w + quad * 4 + r)) s = -INFINITY;
                sacc[nt][r] = s;
                mx = fmaxf(mx, s);
            }
#pragma unroll
            for (int off = 1; off < 16; off <<= 1)
                mx = fmaxf(mx, __shfl_xor(mx, off, 64));
            float mn = fmaxf(m_i[r], mx);
            alpha[r] = __expf(m_i[r] - mn);
            float lsum = 0.f;
#pragma unroll
            for (int nt = 0; nt < 4; ++nt) {
                float e = __expf(sacc[nt][r] - mn);
                sacc[nt][r] = e;
                lsum += e;
            }
#pragma unroll
            for (int off = 1; off < 16; off <<= 1)
                lsum += __shfl_xor(lsum, off, 64);
            l_i[r] = l_i[r] * alpha[r] + lsum;
            m_i[r] = mn;
        }

        // ---- P (C-layout) -> LDS swizzled, own strip only (no barrier needed)
#pragma unroll
        for (int nt = 0; nt < 4; ++nt)
#pragma unroll
            for (int r = 0; r < 4; ++r) {
                int row = 16 * w + quad * 4 + r;
                int c = nt * 16 + l16;
                Ps[row * 64 + ((c >> 3) ^ (row & 7)) * 8 + (c & 7)] = __float2bfloat16(sacc[nt][r]);
            }

        // ---- rescale O, then O += P V
#pragma unroll
        for (int nt = 0; nt < 8; ++nt)
#pragma unroll
            for (int r = 0; r < 4; ++r)
                O[nt][r] *= alpha[r];

#pragma unroll
        for (int ks = 0; ks < 2; ++ks) {
            short8 pa = *(const short8*)&Ps[(16 * w + l16) * 64 + ((ks * 4 + quad) ^ sw7) * 8];
#pragma unroll
            for (int nt = 0; nt < 8; ++nt) {
                short8 vb = *(const short8*)&Vt[(nt * 16 + l16) * 64 + ((ks * 4 + quad) ^ sw7) * 8];
                O[nt] = __builtin_amdgcn_mfma_f32_16x16x32_bf16(pa, vb, O[nt], 0, 0, 0);
            }
        }
    }

    // ---- normalize + store
#pragma unroll
    for (int r = 0; r < 4; ++r) {
        float inv = 1.f / l_i[r];
        bf16* orow = out + (size_t)(s0 + 16 * w + quad * 4 + r) * DIM + h * HD + l16;
#pragma unroll
        for (int nt = 0; nt < 8; ++nt)
            orow[nt * 16] = __float2bfloat16(O[nt][r] * inv);
    }
}

// ---------------------------------------------------------------- launch
extern "C" void kernel_launch(void* const* d_in, const int* in_sizes, int n_in,
                              void* d_out, int out_size, void* d_ws, size_t ws_size,
                              hipStream_t stream) {
    const float* x      = (const float*)d_in[0];
    const float* f_cos  = (const float*)d_in[1];
    const float* f_sin  = (const float*)d_in[2];
    // d_in[3] = mask : ignored (causality analytic)
    const float* wq     = (const float*)d_in[4];
    const float* wk     = (const float*)d_in[5];
    const float* wv     = (const float*)d_in[6];
    const float* wo     = (const float*)d_in[7];
    const float* w1     = (const float*)d_in[8];
    const float* w2     = (const float*)d_in[9];
    const float* w3     = (const float*)d_in[10];
    const float* g_attn = (const float*)d_in[11];
    const float* g_ffn  = (const float*)d_in[12];
    float* out = (float*)d_out;

    char* base = (char*)d_ws;
    size_t off = 0;
    auto alloc = [&](size_t bytes) { void* p = base + off; off += (bytes + 255) & ~255ULL; return p; };
    bf16* qkvt = (bf16*)alloc((size_t)QKVN * DIM * 2);      // wq|wk|wv transposed
    bf16* wot  = (bf16*)alloc((size_t)DIM * DIM * 2);
    bf16* w13t = (bf16*)alloc((size_t)2 * HIDDEN * DIM * 2); // w1t|w3t contiguous
    bf16* w2t  = (bf16*)alloc((size_t)DIM * HIDDEN * 2);
    bf16* xbuf = (bf16*)alloc((size_t)SEQ * DIM * 2);       // xn / attn / hn
    bf16* qkv  = (bf16*)alloc((size_t)SEQ * QKVN * 2);
    float* h   = (float*)alloc((size_t)SEQ * DIM * 4);
    bf16* t1   = (bf16*)alloc((size_t)SEQ * HIDDEN * 2);
    bf16* w1t = w13t;
    bf16* w3t = w13t + (size_t)HIDDEN * DIM;

    dim3 blk(256);

    // ---- weight cast+transpose (4 dispatches)
    cvt_t_kernel<<<dim3(DIM / 64, DIM / 64, 3), blk, 0, stream>>>(wq, wk, wv, qkvt, DIM, DIM);
    cvt_t_kernel<<<dim3(DIM / 64, DIM / 64, 1), blk, 0, stream>>>(wo, wo, wo, wot, DIM, DIM);
    cvt_t_kernel<<<dim3(HIDDEN / 64, DIM / 64, 2), blk, 0, stream>>>(w1, w3, w3, w13t, DIM, HIDDEN);
    cvt_t_kernel<<<dim3(DIM / 64, HIDDEN / 64, 1), blk, 0, stream>>>(w2, w2, w2, w2t, HIDDEN, DIM);

    // ---- 1. xn = rmsnorm(x)
    rmsnorm_kernel<<<SEQ, blk, 0, stream>>>(x, g_attn, xbuf);
    // ---- 2. qkv = xn @ [wq|wk|wv]
    gemm_bf16<0><<<dim3(QKVN / 128, SEQ / 128), blk, 0, stream>>>(xbuf, qkvt, qkv, nullptr, DIM, QKVN);
    // ---- 3. rope
    rope_kernel<<<(SEQ * NHEAD * HD / 2) / 256, blk, 0, stream>>>(qkv, f_cos, f_sin);
    // ---- 4. attn -> xbuf
    flash_attn_mfma<<<dim3(512), blk, 0, stream>>>(qkv, xbuf);
    // ---- 5. h = attn @ wo + x
    gemm_bf16<1><<<dim3(DIM / 128, SEQ / 128), blk, 0, stream>>>(xbuf, wot, h, x, DIM, DIM);
    // ---- 6. hn = rmsnorm(h)
    rmsnorm_kernel<<<SEQ, blk, 0, stream>>>(h, g_ffn, xbuf);
    // ---- 7. t1 = silu(hn @ w1) * (hn @ w3)   [fused]
    gemm_swiglu<<<dim3(HIDDEN / 128, SEQ / 128), blk, 0, stream>>>(xbuf, w1t, w3t, t1, DIM, HIDDEN);
    // ---- 8. out = t1 @ w2 + h
    gemm_bf16<1><<<dim3(DIM / 128, SEQ / 128), blk, 0, stream>>>(t1, w2t, out, h, HIDDEN, DIM);
}